// Round 1
// baseline (176.205 us; speedup 1.0000x reference)
//
#include <hip/hip_runtime.h>
#include <hip/hip_bf16.h>

typedef __attribute__((ext_vector_type(8))) short short8;
typedef __attribute__((ext_vector_type(4))) float f32x4;

#define B_  8
#define L_  2048
#define T_  512
#define DH_ 1024
#define DG_ 768
#define P_  256

__device__ __forceinline__ short f2bf(float x) {
    union { float f; unsigned u; } v; v.f = x;
    unsigned r = v.u + 0x7fffu + ((v.u >> 16) & 1u);
    return (short)(r >> 16);
}

// Transpose f32 [R,C] -> bf16 [C,R], batched via blockIdx.z.
__global__ __launch_bounds__(256) void transpose_bf16_k(
    const float* __restrict__ src, short* __restrict__ dst,
    int R, int C, long sSrc, long sDst)
{
    __shared__ float tile[32][33];
    const int b  = blockIdx.z;
    const int r0 = blockIdx.x * 32, c0 = blockIdx.y * 32;
    const float* s = src + (long)b * sSrc;
    short* d = dst + (long)b * sDst;
    const int x = threadIdx.x & 31, y = threadIdx.x >> 5;
    #pragma unroll
    for (int i = 0; i < 32; i += 8)
        tile[y + i][x] = s[(long)(r0 + y + i) * C + (c0 + x)];
    __syncthreads();
    #pragma unroll
    for (int i = 0; i < 32; i += 8)
        d[(long)(c0 + y + i) * R + (r0 + x)] = f2bf(tile[x][y + i]);
}

// C[M,N] = A[M,K] * B[N,K]^T  (rows-dot-rows). A f32 (converted) or bf16;
// B bf16; C f32 or bf16. Batched via blockIdx.z. 64x64 tile, K-step 32.
template<bool AF32, bool CF32>
__global__ __launch_bounds__(256) void gemm_bt(
    const void* __restrict__ Ap, const short* __restrict__ Bp,
    void* __restrict__ Cp, int M, int N, int K, long sA, long sB, long sC)
{
    __shared__ __align__(16) short As[64][32];
    __shared__ __align__(16) short Bs[64][32];
    const int b  = blockIdx.z;
    const int m0 = blockIdx.y * 64, n0 = blockIdx.x * 64;
    const int t  = threadIdx.x, w = t >> 6, l = t & 63;
    const int ar = t >> 2, ac = (t & 3) * 8;      // staging coords
    const int rl = l & 15, kg = l >> 4;           // fragment coords
    const short* Bb = Bp + (long)b * sB;

    f32x4 acc[4];
    #pragma unroll
    for (int s = 0; s < 4; s++) { acc[s][0]=0.f; acc[s][1]=0.f; acc[s][2]=0.f; acc[s][3]=0.f; }

    for (int k0 = 0; k0 < K; k0 += 32) {
        __syncthreads();
        if (AF32) {
            const float* Af = (const float*)Ap + (long)b * sA + (long)(m0 + ar) * K + k0 + ac;
            float4 v0 = *(const float4*)Af;
            float4 v1 = *(const float4*)(Af + 4);
            short8 sv;
            sv[0]=f2bf(v0.x); sv[1]=f2bf(v0.y); sv[2]=f2bf(v0.z); sv[3]=f2bf(v0.w);
            sv[4]=f2bf(v1.x); sv[5]=f2bf(v1.y); sv[6]=f2bf(v1.z); sv[7]=f2bf(v1.w);
            *(short8*)&As[ar][ac] = sv;
        } else {
            const short* Ab = (const short*)Ap + (long)b * sA + (long)(m0 + ar) * K + k0 + ac;
            *(short8*)&As[ar][ac] = *(const short8*)Ab;
        }
        *(short8*)&Bs[ar][ac] = *(const short8*)(Bb + (long)(n0 + ar) * K + k0 + ac);
        __syncthreads();
        short8 a = *(short8*)&As[w * 16 + rl][kg * 8];
        #pragma unroll
        for (int s = 0; s < 4; s++) {
            short8 bf = *(short8*)&Bs[s * 16 + rl][kg * 8];
            acc[s] = __builtin_amdgcn_mfma_f32_16x16x32_bf16(a, bf, acc[s], 0, 0, 0);
        }
    }
    const int rowb = m0 + w * 16 + kg * 4;
    #pragma unroll
    for (int s = 0; s < 4; s++) {
        const int n = n0 + s * 16 + rl;
        #pragma unroll
        for (int i = 0; i < 4; i++) {
            if (CF32)
                ((float*)Cp)[(long)b * sC + (long)(rowb + i) * N + n] = acc[s][i];
            else
                ((short*)Cp)[(long)b * sC + (long)(rowb + i) * N + n] = f2bf(acc[s][i]);
        }
    }
}

// Fused S = Q K^T * scale (+mask), row-softmax over L, write alpha bf16.
// One block per (b, 16-query tile); 8 waves, each owns 256 keys.
__global__ __launch_bounds__(512) void qk_softmax(
    const short* __restrict__ Qb, const short* __restrict__ Kb,
    const unsigned char* __restrict__ mask, short* __restrict__ alpha)
{
    const int b  = blockIdx.y, q0 = blockIdx.x * 16;
    const int t  = threadIdx.x, w = t >> 6, l = t & 63;
    const int rl = l & 15, kg = l >> 4;
    const short* Qrow  = Qb + ((long)b * T_ + q0) * P_;
    const short* Kbase = Kb + (long)b * L_ * P_;

    f32x4 acc[16];
    #pragma unroll
    for (int s = 0; s < 16; s++) { acc[s][0]=0.f; acc[s][1]=0.f; acc[s][2]=0.f; acc[s][3]=0.f; }

    #pragma unroll
    for (int k0 = 0; k0 < P_; k0 += 32) {
        short8 a = *(const short8*)(Qrow + rl * P_ + k0 + kg * 8);
        #pragma unroll
        for (int s = 0; s < 16; s++) {
            const int key = w * 256 + s * 16 + rl;
            short8 bf = *(const short8*)(Kbase + (long)key * P_ + k0 + kg * 8);
            acc[s] = __builtin_amdgcn_mfma_f32_16x16x32_bf16(a, bf, acc[s], 0, 0, 0);
        }
    }

    const float scale = 0.0625f;  // P^-0.5 = 1/16
    const int keybase = w * 256 + rl;
    #pragma unroll
    for (int s = 0; s < 16; s++) {
        const bool mk = mask[b * L_ + keybase + s * 16] != 0;
        #pragma unroll
        for (int i = 0; i < 4; i++)
            acc[s][i] = mk ? -1e30f : acc[s][i] * scale;
    }

    __shared__ float redmax[16][8];
    __shared__ float redsum[16][8];
    float pm[4], ps[4], m[4], inv[4];

    #pragma unroll
    for (int i = 0; i < 4; i++) pm[i] = acc[0][i];
    #pragma unroll
    for (int s = 1; s < 16; s++)
        #pragma unroll
        for (int i = 0; i < 4; i++) pm[i] = fmaxf(pm[i], acc[s][i]);
    #pragma unroll
    for (int off = 1; off < 16; off <<= 1)
        #pragma unroll
        for (int i = 0; i < 4; i++) pm[i] = fmaxf(pm[i], __shfl_xor(pm[i], off));
    if (rl == 0) {
        #pragma unroll
        for (int i = 0; i < 4; i++) redmax[kg * 4 + i][w] = pm[i];
    }
    __syncthreads();
    #pragma unroll
    for (int i = 0; i < 4; i++) {
        float mm = redmax[kg * 4 + i][0];
        #pragma unroll
        for (int ww = 1; ww < 8; ww++) mm = fmaxf(mm, redmax[kg * 4 + i][ww]);
        m[i] = mm;
        ps[i] = 0.f;
    }
    #pragma unroll
    for (int s = 0; s < 16; s++)
        #pragma unroll
        for (int i = 0; i < 4; i++) {
            acc[s][i] = __expf(acc[s][i] - m[i]);
            ps[i] += acc[s][i];
        }
    #pragma unroll
    for (int off = 1; off < 16; off <<= 1)
        #pragma unroll
        for (int i = 0; i < 4; i++) ps[i] += __shfl_xor(ps[i], off);
    if (rl == 0) {
        #pragma unroll
        for (int i = 0; i < 4; i++) redsum[kg * 4 + i][w] = ps[i];
    }
    __syncthreads();
    #pragma unroll
    for (int i = 0; i < 4; i++) {
        float ss = 0.f;
        #pragma unroll
        for (int ww = 0; ww < 8; ww++) ss += redsum[kg * 4 + i][ww];
        inv[i] = 1.0f / ss;
    }
    #pragma unroll
    for (int s = 0; s < 16; s++)
        #pragma unroll
        for (int i = 0; i < 4; i++)
            alpha[((long)b * T_ + q0 + kg * 4 + i) * L_ + keybase + s * 16] =
                f2bf(acc[s][i] * inv[i]);
}

extern "C" void kernel_launch(void* const* d_in, const int* in_sizes, int n_in,
                              void* d_out, int out_size, void* d_ws, size_t ws_size,
                              hipStream_t stream)
{
    const float* H  = (const float*)d_in[0];
    const float* G  = (const float*)d_in[1];
    const float* Wk = (const float*)d_in[2];
    const float* Wq = (const float*)d_in[3];
    const unsigned char* mask = (const unsigned char*)d_in[4];
    float* Z = (float*)d_out;

    char* ws = (char*)d_ws;
    const long OFF_WKT   = 0;                       // 256x1024 bf16 = 512 KB
    const long OFF_WQT   = 524288;                  // 256x768  bf16 = 384 KB
    const long OFF_HT    = 917504;                  // 8x1024x2048 bf16 = 32 MB
    const long OFF_KB    = OFF_HT + 33554432;       // 8x2048x256 bf16 = 8 MB
    const long OFF_QB    = OFF_KB + 8388608;        // 8x512x256 bf16 = 2 MB
    const long OFF_ALPHA = OFF_QB + 2097152;        // 8x512x2048 bf16 = 16 MB
    short* WkT   = (short*)(ws + OFF_WKT);
    short* WqT   = (short*)(ws + OFF_WQT);
    short* Ht    = (short*)(ws + OFF_HT);
    short* Kb    = (short*)(ws + OFF_KB);
    short* Qb    = (short*)(ws + OFF_QB);
    short* alpha = (short*)(ws + OFF_ALPHA);

    // 1) weight / H transposes to bf16
    transpose_bf16_k<<<dim3(DH_/32, P_/32, 1), 256, 0, stream>>>(Wk, WkT, DH_, P_, 0, 0);
    transpose_bf16_k<<<dim3(DG_/32, P_/32, 1), 256, 0, stream>>>(Wq, WqT, DG_, P_, 0, 0);
    transpose_bf16_k<<<dim3(L_/32, DH_/32, B_), 256, 0, stream>>>(
        H, Ht, L_, DH_, (long)L_ * DH_, (long)DH_ * L_);

    // 2) K = H @ Wk  -> Kb bf16 [B,L,P]
    gemm_bt<true, false><<<dim3(P_/64, L_/64, B_), 256, 0, stream>>>(
        H, WkT, Kb, L_, P_, DH_, (long)L_ * DH_, 0, (long)L_ * P_);

    // 3) Q = G @ Wq  -> Qb bf16 [B,T,P]
    gemm_bt<true, false><<<dim3(P_/64, T_/64, B_), 256, 0, stream>>>(
        G, WqT, Qb, T_, P_, DG_, (long)T_ * DG_, 0, (long)T_ * P_);

    // 4) alpha = softmax(Q K^T * scale) -> bf16 [B,T,L]
    qk_softmax<<<dim3(T_/16, B_), 512, 0, stream>>>(Qb, Kb, mask, alpha);

    // 5) Z = alpha @ H  (= alpha · Ht^T) -> f32 [B,T,Dh]
    gemm_bt<false, true><<<dim3(DH_/64, T_/64, B_), 256, 0, stream>>>(
        alpha, Ht, Z, T_, DH_, L_, (long)T_ * L_, (long)DH_ * L_, (long)T_ * DH_);
}

// Round 2
// 150.544 us; speedup vs baseline: 1.1705x; 1.1705x over previous
//
#include <hip/hip_runtime.h>
#include <hip/hip_bf16.h>

typedef __attribute__((ext_vector_type(8))) short short8;
typedef __attribute__((ext_vector_type(4))) float f32x4;

#define B_  8
#define L_  2048
#define T_  512
#define DH_ 1024
#define DG_ 768
#define P_  256

__device__ __forceinline__ short f2bf(float x) {
    union { float f; unsigned u; } v; v.f = x;
    unsigned r = v.u + 0x7fffu + ((v.u >> 16) & 1u);
    return (short)(r >> 16);
}

typedef __attribute__((address_space(1))) const void av1_t;
typedef __attribute__((address_space(3))) void av3_t;
__device__ __forceinline__ void gl16(const void* g, void* l) {
    __builtin_amdgcn_global_load_lds((av1_t*)g, (av3_t*)l, 16, 0, 0);
}

// Transpose f32 [R,C] -> bf16 [C,R], batched via blockIdx.z.
__global__ __launch_bounds__(256) void transpose_bf16_k(
    const float* __restrict__ src, short* __restrict__ dst,
    int R, int C, long sSrc, long sDst)
{
    __shared__ float tile[32][33];
    const int b  = blockIdx.z;
    const int r0 = blockIdx.x * 32, c0 = blockIdx.y * 32;
    const float* s = src + (long)b * sSrc;
    short* d = dst + (long)b * sDst;
    const int x = threadIdx.x & 31, y = threadIdx.x >> 5;
    #pragma unroll
    for (int i = 0; i < 32; i += 8)
        tile[y + i][x] = s[(long)(r0 + y + i) * C + (c0 + x)];
    __syncthreads();
    #pragma unroll
    for (int i = 0; i < 32; i += 8)
        d[(long)(c0 + y + i) * R + (r0 + x)] = f2bf(tile[x][y + i]);
}

// C[M,N] = A[M,K] * B[N,K]^T. 4 waves (2x2), BK=64, global_load_lds staging
// for bf16 operands, XOR-swizzled LDS (chunk ^= row&7) to kill the 16-way
// ds_read_b128 bank conflict at 128B row stride. XCD-chunked block swizzle.
template<int BM, int BN, bool AF32, bool CF32>
__global__ __launch_bounds__(256) void gemm_bt2(
    const void* __restrict__ Ap, const short* __restrict__ Bp,
    void* __restrict__ Cp, int M, int N, int K, long sA, long sB, long sC)
{
    constexpr int WM = BM / 2, WN = BN / 2, FM = WM / 16, FN = WN / 16;
    __shared__ __align__(16) short As[BM][64];
    __shared__ __align__(16) short Bs[BN][64];

    // XCD-aware bijective block swizzle (requires nwg % 8 == 0)
    const int gx = gridDim.x, gy = gridDim.y;
    const int nwg = gx * gy * (int)gridDim.z;
    int flat = blockIdx.x + gx * (blockIdx.y + gy * blockIdx.z);
    if ((nwg & 7) == 0) flat = (flat & 7) * (nwg >> 3) + (flat >> 3);
    const int bx = flat % gx, by = (flat / gx) % gy, b = flat / (gx * gy);
    const int m0 = by * BM, n0 = bx * BN;

    const int t = threadIdx.x, w = t >> 6, l = t & 63;
    const int wm = w >> 1, wn = w & 1, rl = l & 15, kg = l >> 4;

    // staging coords: each thread owns one 16B chunk per 32-row group
    const int srow = t >> 3;                 // 0..31
    const int schunk = t & 7;                // 0..7
    const int gchunk = schunk ^ (srow & 7);  // inverse-swizzled global chunk

    const short* Bg0 = Bp + (long)b * sB + (long)(n0 + srow) * K + gchunk * 8;
    char* AsP = (char*)&As[0][0] + t * 16;
    char* BsP = (char*)&Bs[0][0] + t * 16;

    // swizzled read chunk offsets (bytes) for the two k-halves
    const int ch0 = ((0 | kg) ^ (rl & 7)) * 16;
    const int ch1 = ((4 | kg) ^ (rl & 7)) * 16;

    f32x4 acc[FM][FN];
    #pragma unroll
    for (int mi = 0; mi < FM; mi++)
        #pragma unroll
        for (int ni = 0; ni < FN; ni++)
            acc[mi][ni] = (f32x4){0.f, 0.f, 0.f, 0.f};

    for (int k0 = 0; k0 < K; k0 += 64) {
        if (AF32) {
            #pragma unroll
            for (int j = 0; j < BM / 32; j++) {
                const float* ag = (const float*)Ap + (long)b * sA +
                                  (long)(m0 + j * 32 + srow) * K + k0 + schunk * 8;
                float4 v0 = *(const float4*)ag;
                float4 v1 = *(const float4*)(ag + 4);
                short8 sv;
                sv[0]=f2bf(v0.x); sv[1]=f2bf(v0.y); sv[2]=f2bf(v0.z); sv[3]=f2bf(v0.w);
                sv[4]=f2bf(v1.x); sv[5]=f2bf(v1.y); sv[6]=f2bf(v1.z); sv[7]=f2bf(v1.w);
                *(short8*)&As[j * 32 + srow][(schunk ^ (srow & 7)) * 8] = sv;
            }
        } else {
            const short* Ag0 = (const short*)Ap + (long)b * sA +
                               (long)(m0 + srow) * K + k0 + gchunk * 8;
            #pragma unroll
            for (int j = 0; j < BM / 32; j++)
                gl16(Ag0 + (long)j * 32 * K, AsP + j * 4096);
        }
        #pragma unroll
        for (int j = 0; j < BN / 32; j++)
            gl16(Bg0 + k0 + (long)j * 32 * K, BsP + j * 4096);
        __syncthreads();

        #pragma unroll
        for (int kh = 0; kh < 2; kh++) {
            const int ch = kh ? ch1 : ch0;
            short8 a[FM], bb[FN];
            #pragma unroll
            for (int mi = 0; mi < FM; mi++)
                a[mi] = *(short8*)((char*)&As[wm * WM + mi * 16 + rl][0] + ch);
            #pragma unroll
            for (int ni = 0; ni < FN; ni++)
                bb[ni] = *(short8*)((char*)&Bs[wn * WN + ni * 16 + rl][0] + ch);
            #pragma unroll
            for (int mi = 0; mi < FM; mi++)
                #pragma unroll
                for (int ni = 0; ni < FN; ni++)
                    acc[mi][ni] = __builtin_amdgcn_mfma_f32_16x16x32_bf16(
                        a[mi], bb[ni], acc[mi][ni], 0, 0, 0);
        }
        __syncthreads();
    }

    const int rowb = m0 + wm * WM + kg * 4;
    #pragma unroll
    for (int mi = 0; mi < FM; mi++)
        #pragma unroll
        for (int ni = 0; ni < FN; ni++) {
            const int n = n0 + wn * WN + ni * 16 + rl;
            #pragma unroll
            for (int i = 0; i < 4; i++) {
                const long idx = (long)b * sC + (long)(rowb + mi * 16 + i) * N + n;
                if (CF32) ((float*)Cp)[idx] = acc[mi][ni][i];
                else      ((short*)Cp)[idx] = f2bf(acc[mi][ni][i]);
            }
        }
}

// Fused S = Q K^T * scale (+mask), row-softmax over L, write alpha bf16.
__global__ __launch_bounds__(512) void qk_softmax(
    const short* __restrict__ Qb, const short* __restrict__ Kb,
    const unsigned char* __restrict__ mask, short* __restrict__ alpha)
{
    const int b  = blockIdx.y, q0 = blockIdx.x * 16;
    const int t  = threadIdx.x, w = t >> 6, l = t & 63;
    const int rl = l & 15, kg = l >> 4;
    const short* Qrow  = Qb + ((long)b * T_ + q0) * P_;
    const short* Kbase = Kb + (long)b * L_ * P_;

    f32x4 acc[16];
    #pragma unroll
    for (int s = 0; s < 16; s++) { acc[s][0]=0.f; acc[s][1]=0.f; acc[s][2]=0.f; acc[s][3]=0.f; }

    #pragma unroll
    for (int k0 = 0; k0 < P_; k0 += 32) {
        short8 a = *(const short8*)(Qrow + rl * P_ + k0 + kg * 8);
        #pragma unroll
        for (int s = 0; s < 16; s++) {
            const int key = w * 256 + s * 16 + rl;
            short8 bf = *(const short8*)(Kbase + (long)key * P_ + k0 + kg * 8);
            acc[s] = __builtin_amdgcn_mfma_f32_16x16x32_bf16(a, bf, acc[s], 0, 0, 0);
        }
    }

    const float scale = 0.0625f;  // P^-0.5
    const int keybase = w * 256 + rl;
    #pragma unroll
    for (int s = 0; s < 16; s++) {
        const bool mk = mask[b * L_ + keybase + s * 16] != 0;
        #pragma unroll
        for (int i = 0; i < 4; i++)
            acc[s][i] = mk ? -1e30f : acc[s][i] * scale;
    }

    __shared__ float redmax[16][8];
    __shared__ float redsum[16][8];
    float pm[4], ps[4], m[4], inv[4];

    #pragma unroll
    for (int i = 0; i < 4; i++) pm[i] = acc[0][i];
    #pragma unroll
    for (int s = 1; s < 16; s++)
        #pragma unroll
        for (int i = 0; i < 4; i++) pm[i] = fmaxf(pm[i], acc[s][i]);
    #pragma unroll
    for (int off = 1; off < 16; off <<= 1)
        #pragma unroll
        for (int i = 0; i < 4; i++) pm[i] = fmaxf(pm[i], __shfl_xor(pm[i], off));
    if (rl == 0) {
        #pragma unroll
        for (int i = 0; i < 4; i++) redmax[kg * 4 + i][w] = pm[i];
    }
    __syncthreads();
    #pragma unroll
    for (int i = 0; i < 4; i++) {
        float mm = redmax[kg * 4 + i][0];
        #pragma unroll
        for (int ww = 1; ww < 8; ww++) mm = fmaxf(mm, redmax[kg * 4 + i][ww]);
        m[i] = mm;
        ps[i] = 0.f;
    }
    #pragma unroll
    for (int s = 0; s < 16; s++)
        #pragma unroll
        for (int i = 0; i < 4; i++) {
            acc[s][i] = __expf(acc[s][i] - m[i]);
            ps[i] += acc[s][i];
        }
    #pragma unroll
    for (int off = 1; off < 16; off <<= 1)
        #pragma unroll
        for (int i = 0; i < 4; i++) ps[i] += __shfl_xor(ps[i], off);
    if (rl == 0) {
        #pragma unroll
        for (int i = 0; i < 4; i++) redsum[kg * 4 + i][w] = ps[i];
    }
    __syncthreads();
    #pragma unroll
    for (int i = 0; i < 4; i++) {
        float ss = 0.f;
        #pragma unroll
        for (int ww = 0; ww < 8; ww++) ss += redsum[kg * 4 + i][ww];
        inv[i] = 1.0f / ss;
    }
    #pragma unroll
    for (int s = 0; s < 16; s++)
        #pragma unroll
        for (int i = 0; i < 4; i++)
            alpha[((long)b * T_ + q0 + kg * 4 + i) * L_ + keybase + s * 16] =
                f2bf(acc[s][i] * inv[i]);
}

extern "C" void kernel_launch(void* const* d_in, const int* in_sizes, int n_in,
                              void* d_out, int out_size, void* d_ws, size_t ws_size,
                              hipStream_t stream)
{
    const float* H  = (const float*)d_in[0];
    const float* G  = (const float*)d_in[1];
    const float* Wk = (const float*)d_in[2];
    const float* Wq = (const float*)d_in[3];
    const unsigned char* mask = (const unsigned char*)d_in[4];
    float* Z = (float*)d_out;

    char* ws = (char*)d_ws;
    const long OFF_WKT   = 0;                       // 256x1024 bf16 = 512 KB
    const long OFF_WQT   = 524288;                  // 256x768  bf16 = 384 KB
    const long OFF_HT    = 917504;                  // 8x1024x2048 bf16 = 32 MB
    const long OFF_KB    = OFF_HT + 33554432;       // 8x2048x256 bf16 = 8 MB
    const long OFF_QB    = OFF_KB + 8388608;        // 8x512x256 bf16 = 2 MB
    const long OFF_ALPHA = OFF_QB + 2097152;        // 8x512x2048 bf16 = 16 MB
    short* WkT   = (short*)(ws + OFF_WKT);
    short* WqT   = (short*)(ws + OFF_WQT);
    short* Ht    = (short*)(ws + OFF_HT);
    short* Kb    = (short*)(ws + OFF_KB);
    short* Qb    = (short*)(ws + OFF_QB);
    short* alpha = (short*)(ws + OFF_ALPHA);

    // 1) weight / H transposes to bf16
    transpose_bf16_k<<<dim3(DH_/32, P_/32, 1), 256, 0, stream>>>(Wk, WkT, DH_, P_, 0, 0);
    transpose_bf16_k<<<dim3(DG_/32, P_/32, 1), 256, 0, stream>>>(Wq, WqT, DG_, P_, 0, 0);
    transpose_bf16_k<<<dim3(L_/32, DH_/32, B_), 256, 0, stream>>>(
        H, Ht, L_, DH_, (long)L_ * DH_, (long)DH_ * L_);

    // 2) K = H @ Wk -> bf16 [B,L,P]   (512 blocks = 2/CU)
    gemm_bt2<128, 64, true, false><<<dim3(P_/64, L_/128, B_), 256, 0, stream>>>(
        H, WkT, Kb, L_, P_, DH_, (long)L_ * DH_, 0, (long)L_ * P_);

    // 3) Q = G @ Wq -> bf16 [B,T,P]   (256 blocks)
    gemm_bt2<64, 64, true, false><<<dim3(P_/64, T_/64, B_), 256, 0, stream>>>(
        G, WqT, Qb, T_, P_, DG_, (long)T_ * DG_, 0, (long)T_ * P_);

    // 4) alpha = softmax(Q K^T * scale) -> bf16 [B,T,L]
    qk_softmax<<<dim3(T_/16, B_), 512, 0, stream>>>(Qb, Kb, mask, alpha);

    // 5) Z = alpha @ H = alpha · Ht^T -> f32 [B,T,Dh]   (512 blocks = 2/CU)
    gemm_bt2<128, 64, false, true><<<dim3(DH_/64, T_/128, B_), 256, 0, stream>>>(
        alpha, Ht, Z, T_, DH_, L_, (long)T_ * L_, (long)DH_ * L_, (long)T_ * DH_);
}

// Round 3
// 126.594 us; speedup vs baseline: 1.3919x; 1.1892x over previous
//
#include <hip/hip_runtime.h>
#include <hip/hip_bf16.h>

typedef __attribute__((ext_vector_type(8))) short short8;
typedef __attribute__((ext_vector_type(4))) float f32x4;

#define B_  8
#define L_  2048
#define T_  512
#define DH_ 1024
#define DG_ 768
#define P_  256

__device__ __forceinline__ short f2bf(float x) {
    union { float f; unsigned u; } v; v.f = x;
    unsigned r = v.u + 0x7fffu + ((v.u >> 16) & 1u);
    return (short)(r >> 16);
}
__device__ __forceinline__ float bf2f(short s) {
    union { unsigned u; float f; } v; v.u = ((unsigned)(unsigned short)s) << 16;
    return v.f;
}

typedef __attribute__((address_space(1))) const void av1_t;
typedef __attribute__((address_space(3))) void av3_t;
__device__ __forceinline__ void gl16(const void* g, void* l) {
    __builtin_amdgcn_global_load_lds((av1_t*)g, (av3_t*)l, 16, 0, 0);
}

// Transpose f32 [R,C] -> bf16 [C,R], batched via blockIdx.z.
__global__ __launch_bounds__(256) void transpose_bf16_k(
    const float* __restrict__ src, short* __restrict__ dst,
    int R, int C, long sSrc, long sDst)
{
    __shared__ float tile[32][33];
    const int b  = blockIdx.z;
    const int r0 = blockIdx.x * 32, c0 = blockIdx.y * 32;
    const float* s = src + (long)b * sSrc;
    short* d = dst + (long)b * sDst;
    const int x = threadIdx.x & 31, y = threadIdx.x >> 5;
    #pragma unroll
    for (int i = 0; i < 32; i += 8)
        tile[y + i][x] = s[(long)(r0 + y + i) * C + (c0 + x)];
    __syncthreads();
    #pragma unroll
    for (int i = 0; i < 32; i += 8)
        d[(long)(c0 + y + i) * R + (r0 + x)] = f2bf(tile[x][y + i]);
}

// C[M,N] = cscale * A[M,K] * B[N,K]^T. 4 waves (2x2), BK=64, global_load_lds
// staging for bf16 operands, XOR-swizzled LDS, XCD-chunked block swizzle.
template<int BM, int BN, bool AF32, bool CF32>
__global__ __launch_bounds__(256) void gemm_bt2(
    const void* __restrict__ Ap, const short* __restrict__ Bp,
    void* __restrict__ Cp, int M, int N, int K, long sA, long sB, long sC,
    float cscale)
{
    constexpr int WM = BM / 2, WN = BN / 2, FM = WM / 16, FN = WN / 16;
    __shared__ __align__(16) short As[BM][64];
    __shared__ __align__(16) short Bs[BN][64];

    const int gx = gridDim.x, gy = gridDim.y;
    const int nwg = gx * gy * (int)gridDim.z;
    int flat = blockIdx.x + gx * (blockIdx.y + gy * blockIdx.z);
    if ((nwg & 7) == 0) flat = (flat & 7) * (nwg >> 3) + (flat >> 3);
    const int bx = flat % gx, by = (flat / gx) % gy, b = flat / (gx * gy);
    const int m0 = by * BM, n0 = bx * BN;

    const int t = threadIdx.x, w = t >> 6, l = t & 63;
    const int wm = w >> 1, wn = w & 1, rl = l & 15, kg = l >> 4;

    const int srow = t >> 3;
    const int schunk = t & 7;
    const int gchunk = schunk ^ (srow & 7);

    const short* Bg0 = Bp + (long)b * sB + (long)(n0 + srow) * K + gchunk * 8;
    char* AsP = (char*)&As[0][0] + t * 16;
    char* BsP = (char*)&Bs[0][0] + t * 16;

    const int ch0 = ((0 | kg) ^ (rl & 7)) * 16;
    const int ch1 = ((4 | kg) ^ (rl & 7)) * 16;

    f32x4 acc[FM][FN];
    #pragma unroll
    for (int mi = 0; mi < FM; mi++)
        #pragma unroll
        for (int ni = 0; ni < FN; ni++)
            acc[mi][ni] = (f32x4){0.f, 0.f, 0.f, 0.f};

    for (int k0 = 0; k0 < K; k0 += 64) {
        if (AF32) {
            #pragma unroll
            for (int j = 0; j < BM / 32; j++) {
                const float* ag = (const float*)Ap + (long)b * sA +
                                  (long)(m0 + j * 32 + srow) * K + k0 + schunk * 8;
                float4 v0 = *(const float4*)ag;
                float4 v1 = *(const float4*)(ag + 4);
                short8 sv;
                sv[0]=f2bf(v0.x); sv[1]=f2bf(v0.y); sv[2]=f2bf(v0.z); sv[3]=f2bf(v0.w);
                sv[4]=f2bf(v1.x); sv[5]=f2bf(v1.y); sv[6]=f2bf(v1.z); sv[7]=f2bf(v1.w);
                *(short8*)&As[j * 32 + srow][(schunk ^ (srow & 7)) * 8] = sv;
            }
        } else {
            const short* Ag0 = (const short*)Ap + (long)b * sA +
                               (long)(m0 + srow) * K + k0 + gchunk * 8;
            #pragma unroll
            for (int j = 0; j < BM / 32; j++)
                gl16(Ag0 + (long)j * 32 * K, AsP + j * 4096);
        }
        #pragma unroll
        for (int j = 0; j < BN / 32; j++)
            gl16(Bg0 + k0 + (long)j * 32 * K, BsP + j * 4096);
        __syncthreads();

        #pragma unroll
        for (int kh = 0; kh < 2; kh++) {
            const int ch = kh ? ch1 : ch0;
            short8 a[FM], bb[FN];
            #pragma unroll
            for (int mi = 0; mi < FM; mi++)
                a[mi] = *(short8*)((char*)&As[wm * WM + mi * 16 + rl][0] + ch);
            #pragma unroll
            for (int ni = 0; ni < FN; ni++)
                bb[ni] = *(short8*)((char*)&Bs[wn * WN + ni * 16 + rl][0] + ch);
            #pragma unroll
            for (int mi = 0; mi < FM; mi++)
                #pragma unroll
                for (int ni = 0; ni < FN; ni++)
                    acc[mi][ni] = __builtin_amdgcn_mfma_f32_16x16x32_bf16(
                        a[mi], bb[ni], acc[mi][ni], 0, 0, 0);
        }
        __syncthreads();
    }

    const int rowb = m0 + wm * WM + kg * 4;
    #pragma unroll
    for (int mi = 0; mi < FM; mi++)
        #pragma unroll
        for (int ni = 0; ni < FN; ni++) {
            const int n = n0 + wn * WN + ni * 16 + rl;
            #pragma unroll
            for (int i = 0; i < 4; i++) {
                const long idx = (long)b * sC + (long)(rowb + mi * 16 + i) * N + n;
                const float v = acc[mi][ni][i] * cscale;
                if (CF32) ((float*)Cp)[idx] = v;
                else      ((short*)Cp)[idx] = f2bf(v);
            }
        }
}

// In-place row softmax over bf16 logits [B*T, L], with key mask [B, L].
// One wave per row; loads whole row to registers, reduces, stores bf16.
__global__ __launch_bounds__(256) void softmax_rows(
    short* __restrict__ logits, const unsigned char* __restrict__ mask)
{
    const int w = threadIdx.x >> 6, l = threadIdx.x & 63;
    const int r = blockIdx.x * 4 + w;       // row in [0, B*T)
    const int b = r / T_;
    short* row = logits + (long)r * L_;
    const unsigned char* mrow = mask + (long)b * L_;

    float v[32];
    #pragma unroll
    for (int c = 0; c < 4; c++) {
        const int e0 = (c * 64 + l) * 8;
        short8 raw = *(const short8*)(row + e0);
        unsigned long long mk = *(const unsigned long long*)(mrow + e0);
        #pragma unroll
        for (int i = 0; i < 8; i++) {
            float x = bf2f(raw[i]);
            v[c * 8 + i] = ((mk >> (8 * i)) & 0xffull) ? -1e30f : x;
        }
    }
    float m = v[0];
    #pragma unroll
    for (int i = 1; i < 32; i++) m = fmaxf(m, v[i]);
    #pragma unroll
    for (int off = 1; off < 64; off <<= 1) m = fmaxf(m, __shfl_xor(m, off));

    float s = 0.f;
    #pragma unroll
    for (int i = 0; i < 32; i++) { v[i] = __expf(v[i] - m); s += v[i]; }
    #pragma unroll
    for (int off = 1; off < 64; off <<= 1) s += __shfl_xor(s, off);
    const float inv = 1.0f / s;

    #pragma unroll
    for (int c = 0; c < 4; c++) {
        const int e0 = (c * 64 + l) * 8;
        short8 outv;
        #pragma unroll
        for (int i = 0; i < 8; i++) outv[i] = f2bf(v[c * 8 + i] * inv);
        *(short8*)(row + e0) = outv;
    }
}

extern "C" void kernel_launch(void* const* d_in, const int* in_sizes, int n_in,
                              void* d_out, int out_size, void* d_ws, size_t ws_size,
                              hipStream_t stream)
{
    const float* H  = (const float*)d_in[0];
    const float* G  = (const float*)d_in[1];
    const float* Wk = (const float*)d_in[2];
    const float* Wq = (const float*)d_in[3];
    const unsigned char* mask = (const unsigned char*)d_in[4];
    float* Z = (float*)d_out;

    char* ws = (char*)d_ws;
    const long OFF_WKT   = 0;                       // 256x1024 bf16 = 512 KB
    const long OFF_WQT   = 524288;                  // 256x768  bf16 = 384 KB
    const long OFF_HT    = 917504;                  // 8x1024x2048 bf16 = 32 MB
    const long OFF_KB    = OFF_HT + 33554432;       // 8x2048x256 bf16 = 8 MB
    const long OFF_QB    = OFF_KB + 8388608;        // 8x512x256 bf16 = 2 MB
    const long OFF_ALPHA = OFF_QB + 2097152;        // 8x512x2048 bf16 = 16 MB
    short* WkT   = (short*)(ws + OFF_WKT);
    short* WqT   = (short*)(ws + OFF_WQT);
    short* Ht    = (short*)(ws + OFF_HT);
    short* Kb    = (short*)(ws + OFF_KB);
    short* Qb    = (short*)(ws + OFF_QB);
    short* alpha = (short*)(ws + OFF_ALPHA);        // logits, then alpha in-place

    // 1) weight / H transposes to bf16
    transpose_bf16_k<<<dim3(DH_/32, P_/32, 1), 256, 0, stream>>>(Wk, WkT, DH_, P_, 0, 0);
    transpose_bf16_k<<<dim3(DG_/32, P_/32, 1), 256, 0, stream>>>(Wq, WqT, DG_, P_, 0, 0);
    transpose_bf16_k<<<dim3(L_/32, DH_/32, B_), 256, 0, stream>>>(
        H, Ht, L_, DH_, (long)L_ * DH_, (long)DH_ * L_);

    // 2) K = H @ Wk -> bf16 [B,L,P]
    gemm_bt2<128, 64, true, false><<<dim3(P_/64, L_/128, B_), 256, 0, stream>>>(
        H, WkT, Kb, L_, P_, DH_, (long)L_ * DH_, 0, (long)L_ * P_, 1.0f);

    // 3) Q = (G @ Wq) * P^-0.5 -> bf16 [B,T,P]  (scale folded here)
    gemm_bt2<64, 64, true, false><<<dim3(P_/64, T_/64, B_), 256, 0, stream>>>(
        G, WqT, Qb, T_, P_, DG_, (long)T_ * DG_, 0, (long)T_ * P_, 0.0625f);

    // 4) logits = Q K^T -> bf16 [B,T,L]  (1024 blocks, 4/CU)
    gemm_bt2<128, 64, false, false><<<dim3(L_/64, T_/128, B_), 256, 0, stream>>>(
        Qb, Kb, alpha, T_, L_, P_, (long)T_ * P_, (long)L_ * P_, (long)T_ * L_, 1.0f);

    // 5) row softmax in place (mask applied here)
    softmax_rows<<<dim3(B_ * T_ / 4), 256, 0, stream>>>(alpha, mask);

    // 6) Z = alpha @ H = alpha · Ht^T -> f32 [B,T,Dh]
    gemm_bt2<128, 64, false, true><<<dim3(DH_/64, T_/128, B_), 256, 0, stream>>>(
        alpha, Ht, Z, T_, DH_, L_, (long)T_ * L_, (long)DH_ * L_, (long)T_ * DH_, 1.0f);
}

// Round 4
// 112.100 us; speedup vs baseline: 1.5719x; 1.1293x over previous
//
#include <hip/hip_runtime.h>
#include <hip/hip_bf16.h>

typedef __attribute__((ext_vector_type(8))) short short8;
typedef __attribute__((ext_vector_type(4))) float f32x4;

#define B_  8
#define L_  2048
#define T_  512
#define DH_ 1024
#define DG_ 768
#define P_  256

__device__ __forceinline__ short f2bf(float x) {
    union { float f; unsigned u; } v; v.f = x;
    unsigned r = v.u + 0x7fffu + ((v.u >> 16) & 1u);
    return (short)(r >> 16);
}
__device__ __forceinline__ float bf2f(short s) {
    union { unsigned u; float f; } v; v.u = ((unsigned)(unsigned short)s) << 16;
    return v.f;
}

typedef __attribute__((address_space(1))) const void av1_t;
typedef __attribute__((address_space(3))) void av3_t;
__device__ __forceinline__ void gl16(const void* g, void* l) {
    __builtin_amdgcn_global_load_lds((av1_t*)g, (av3_t*)l, 16, 0, 0);
}

// Transpose f32 [R,C] -> bf16 [C,R], batched via blockIdx.z.
__global__ __launch_bounds__(256) void transpose_bf16_k(
    const float* __restrict__ src, short* __restrict__ dst,
    int R, int C, long sSrc, long sDst)
{
    __shared__ float tile[32][33];
    const int b  = blockIdx.z;
    const int r0 = blockIdx.x * 32, c0 = blockIdx.y * 32;
    const float* s = src + (long)b * sSrc;
    short* d = dst + (long)b * sDst;
    const int x = threadIdx.x & 31, y = threadIdx.x >> 5;
    #pragma unroll
    for (int i = 0; i < 32; i += 8)
        tile[y + i][x] = s[(long)(r0 + y + i) * C + (c0 + x)];
    __syncthreads();
    #pragma unroll
    for (int i = 0; i < 32; i += 8)
        d[(long)(c0 + y + i) * R + (r0 + x)] = f2bf(tile[x][y + i]);
}

// C[M,N] = A[M,K] * B[N,K]^T, 4 waves (2x2), BK=64, gl16 staging for bf16,
// XOR-swizzled LDS, XCD-chunked block swizzle.
// EPI: 0 = f32 C*cscale, 1 = bf16 C*cscale,
//      2 = QK: e=mask?0:exp(C); write bf16 e + per-row partial sums psum[.][32]
//      3 = PV: f32 C * (1/sum(psum row))
template<int BM, int BN, bool AF32, int EPI>
__global__ __launch_bounds__(256) void gemm_bt2(
    const void* __restrict__ Ap, const short* __restrict__ Bp,
    void* __restrict__ Cp, int M, int N, int K, long sA, long sB, long sC,
    float cscale, const unsigned char* __restrict__ mask,
    float* __restrict__ psum)
{
    constexpr int WM = BM / 2, WN = BN / 2, FM = WM / 16, FN = WN / 16;
    __shared__ __align__(16) short As[BM][64];
    __shared__ __align__(16) short Bs[BN][64];
    __shared__ float invL[BM];

    const int gx = gridDim.x, gy = gridDim.y;
    const int nwg = gx * gy * (int)gridDim.z;
    int flat = blockIdx.x + gx * (blockIdx.y + gy * blockIdx.z);
    if ((nwg & 7) == 0) flat = (flat & 7) * (nwg >> 3) + (flat >> 3);
    const int bx = flat % gx, by = (flat / gx) % gy, b = flat / (gx * gy);
    const int m0 = by * BM, n0 = bx * BN;

    const int t = threadIdx.x, w = t >> 6, l = t & 63;
    const int wm = w >> 1, wn = w & 1, rl = l & 15, kg = l >> 4;

    const int srow = t >> 3;
    const int schunk = t & 7;
    const int gchunk = schunk ^ (srow & 7);

    const short* Bg0 = Bp + (long)b * sB + (long)(n0 + srow) * K + gchunk * 8;
    char* AsP = (char*)&As[0][0] + t * 16;
    char* BsP = (char*)&Bs[0][0] + t * 16;

    const int ch0 = ((0 | kg) ^ (rl & 7)) * 16;
    const int ch1 = ((4 | kg) ^ (rl & 7)) * 16;

    f32x4 acc[FM][FN];
    #pragma unroll
    for (int mi = 0; mi < FM; mi++)
        #pragma unroll
        for (int ni = 0; ni < FN; ni++)
            acc[mi][ni] = (f32x4){0.f, 0.f, 0.f, 0.f};

    for (int k0 = 0; k0 < K; k0 += 64) {
        if (AF32) {
            #pragma unroll
            for (int j = 0; j < BM / 32; j++) {
                const float* ag = (const float*)Ap + (long)b * sA +
                                  (long)(m0 + j * 32 + srow) * K + k0 + schunk * 8;
                float4 v0 = *(const float4*)ag;
                float4 v1 = *(const float4*)(ag + 4);
                short8 sv;
                sv[0]=f2bf(v0.x); sv[1]=f2bf(v0.y); sv[2]=f2bf(v0.z); sv[3]=f2bf(v0.w);
                sv[4]=f2bf(v1.x); sv[5]=f2bf(v1.y); sv[6]=f2bf(v1.z); sv[7]=f2bf(v1.w);
                *(short8*)&As[j * 32 + srow][(schunk ^ (srow & 7)) * 8] = sv;
            }
        } else {
            const short* Ag0 = (const short*)Ap + (long)b * sA +
                               (long)(m0 + srow) * K + k0 + gchunk * 8;
            #pragma unroll
            for (int j = 0; j < BM / 32; j++)
                gl16(Ag0 + (long)j * 32 * K, AsP + j * 4096);
        }
        #pragma unroll
        for (int j = 0; j < BN / 32; j++)
            gl16(Bg0 + k0 + (long)j * 32 * K, BsP + j * 4096);
        __syncthreads();

        #pragma unroll
        for (int kh = 0; kh < 2; kh++) {
            const int ch = kh ? ch1 : ch0;
            short8 a[FM], bb[FN];
            #pragma unroll
            for (int mi = 0; mi < FM; mi++)
                a[mi] = *(short8*)((char*)&As[wm * WM + mi * 16 + rl][0] + ch);
            #pragma unroll
            for (int ni = 0; ni < FN; ni++)
                bb[ni] = *(short8*)((char*)&Bs[wn * WN + ni * 16 + rl][0] + ch);
            #pragma unroll
            for (int mi = 0; mi < FM; mi++)
                #pragma unroll
                for (int ni = 0; ni < FN; ni++)
                    acc[mi][ni] = __builtin_amdgcn_mfma_f32_16x16x32_bf16(
                        a[mi], bb[ni], acc[mi][ni], 0, 0, 0);
        }
        __syncthreads();
    }

    if constexpr (EPI == 3) {
        if (t < BM) {
            const float* pp = psum + ((long)b * M + m0 + t) * 32;
            float s = 0.f;
            #pragma unroll
            for (int j = 0; j < 32; j++) s += pp[j];
            invL[t] = 1.0f / s;
        }
        __syncthreads();
    }

    const int rowb = m0 + wm * WM + kg * 4;

    if constexpr (EPI == 2) {
        float* psL = (float*)&As[0][0];  // [2][BM], each slot written once
        float pr[FM][4];
        #pragma unroll
        for (int mi = 0; mi < FM; mi++)
            #pragma unroll
            for (int i = 0; i < 4; i++) pr[mi][i] = 0.f;
        #pragma unroll
        for (int mi = 0; mi < FM; mi++)
            #pragma unroll
            for (int ni = 0; ni < FN; ni++) {
                const int n = n0 + wn * WN + ni * 16 + rl;
                const bool mk = mask[(long)b * N + n] != 0;
                #pragma unroll
                for (int i = 0; i < 4; i++) {
                    const float e = mk ? 0.f : __expf(acc[mi][ni][i]);
                    ((short*)Cp)[(long)b * sC + (long)(rowb + mi * 16 + i) * N + n] = f2bf(e);
                    pr[mi][i] += e;
                }
            }
        #pragma unroll
        for (int off = 1; off < 16; off <<= 1)
            #pragma unroll
            for (int mi = 0; mi < FM; mi++)
                #pragma unroll
                for (int i = 0; i < 4; i++)
                    pr[mi][i] += __shfl_xor(pr[mi][i], off);
        if (rl == 0) {
            #pragma unroll
            for (int mi = 0; mi < FM; mi++)
                #pragma unroll
                for (int i = 0; i < 4; i++)
                    psL[wn * BM + wm * WM + mi * 16 + kg * 4 + i] = pr[mi][i];
        }
        __syncthreads();
        if (t < BM)
            psum[((long)b * M + m0 + t) * 32 + bx] = psL[t] + psL[BM + t];
        return;
    }

    #pragma unroll
    for (int mi = 0; mi < FM; mi++)
        #pragma unroll
        for (int ni = 0; ni < FN; ni++) {
            const int n = n0 + wn * WN + ni * 16 + rl;
            #pragma unroll
            for (int i = 0; i < 4; i++) {
                const long idx = (long)b * sC + (long)(rowb + mi * 16 + i) * N + n;
                if constexpr (EPI == 0)
                    ((float*)Cp)[idx] = acc[mi][ni][i] * cscale;
                else if constexpr (EPI == 1)
                    ((short*)Cp)[idx] = f2bf(acc[mi][ni][i] * cscale);
                else  // EPI == 3
                    ((float*)Cp)[idx] = acc[mi][ni][i] *
                                        invL[wm * WM + mi * 16 + kg * 4 + i];
            }
        }
}

extern "C" void kernel_launch(void* const* d_in, const int* in_sizes, int n_in,
                              void* d_out, int out_size, void* d_ws, size_t ws_size,
                              hipStream_t stream)
{
    const float* H  = (const float*)d_in[0];
    const float* G  = (const float*)d_in[1];
    const float* Wk = (const float*)d_in[2];
    const float* Wq = (const float*)d_in[3];
    const unsigned char* mask = (const unsigned char*)d_in[4];
    float* Z = (float*)d_out;

    char* ws = (char*)d_ws;
    const long OFF_WKT   = 0;                       // 256x1024 bf16 = 512 KB
    const long OFF_WQT   = 524288;                  // 256x768  bf16 = 384 KB
    const long OFF_HT    = 917504;                  // 8x1024x2048 bf16 = 32 MB
    const long OFF_KB    = OFF_HT + 33554432;       // 8x2048x256 bf16 = 8 MB
    const long OFF_QB    = OFF_KB + 8388608;        // 8x512x256 bf16 = 2 MB
    const long OFF_ALPHA = OFF_QB + 2097152;        // 8x512x2048 bf16 = 16 MB
    const long OFF_PSUM  = OFF_ALPHA + 16777216;    // 8x512x32 f32 = 512 KB
    short* WkT   = (short*)(ws + OFF_WKT);
    short* WqT   = (short*)(ws + OFF_WQT);
    short* Ht    = (short*)(ws + OFF_HT);
    short* Kb    = (short*)(ws + OFF_KB);
    short* Qb    = (short*)(ws + OFF_QB);
    short* alpha = (short*)(ws + OFF_ALPHA);        // unnormalized e = exp(logit)
    float* psum  = (float*)(ws + OFF_PSUM);

    // 1) weight / H transposes to bf16
    transpose_bf16_k<<<dim3(DH_/32, P_/32, 1), 256, 0, stream>>>(Wk, WkT, DH_, P_, 0, 0);
    transpose_bf16_k<<<dim3(DG_/32, P_/32, 1), 256, 0, stream>>>(Wq, WqT, DG_, P_, 0, 0);
    transpose_bf16_k<<<dim3(L_/32, DH_/32, B_), 256, 0, stream>>>(
        H, Ht, L_, DH_, (long)L_ * DH_, (long)DH_ * L_);

    // 2) K = H @ Wk -> bf16 [B,L,P]; 32x256 tile: H read exactly once
    gemm_bt2<32, 256, true, 1><<<dim3(1, L_/32, B_), 256, 0, stream>>>(
        H, WkT, Kb, L_, P_, DH_, (long)L_ * DH_, 0, (long)L_ * P_,
        1.0f, nullptr, nullptr);

    // 3) Q = (G @ Wq) * P^-0.5 -> bf16 [B,T,P]; 32x256 tile
    gemm_bt2<32, 256, true, 1><<<dim3(1, T_/32, B_), 256, 0, stream>>>(
        G, WqT, Qb, T_, P_, DG_, (long)T_ * DG_, 0, (long)T_ * P_,
        0.0625f, nullptr, nullptr);

    // 4) e = exp(Q K^T) (mask->0) -> bf16 [B,T,L] + row partial sums psum
    gemm_bt2<128, 64, false, 2><<<dim3(L_/64, T_/128, B_), 256, 0, stream>>>(
        Qb, Kb, alpha, T_, L_, P_, (long)T_ * P_, (long)L_ * P_, (long)T_ * L_,
        1.0f, mask, psum);

    // 5) Z = (e @ H) / rowsum(e) -> f32 [B,T,Dh]
    gemm_bt2<128, 64, false, 3><<<dim3(DH_/64, T_/128, B_), 256, 0, stream>>>(
        alpha, Ht, Z, T_, DH_, L_, (long)T_ * L_, (long)DH_ * L_, (long)T_ * DH_,
        1.0f, nullptr, psum);
}

// Round 5
// 84.743 us; speedup vs baseline: 2.0793x; 1.3228x over previous
//
#include <hip/hip_runtime.h>
#include <hip/hip_bf16.h>

typedef __attribute__((ext_vector_type(8))) short short8;
typedef __attribute__((ext_vector_type(4))) float f32x4;

#define B_  8
#define L_  2048
#define T_  512
#define DH_ 1024
#define DG_ 768
#define P_  256

__device__ __forceinline__ short f2bf(float x) {
    union { float f; unsigned u; } v; v.f = x;
    unsigned r = v.u + 0x7fffu + ((v.u >> 16) & 1u);
    return (short)(r >> 16);
}

typedef __attribute__((address_space(1))) const void av1_t;
typedef __attribute__((address_space(3))) void av3_t;
__device__ __forceinline__ void gl16(const void* g, void* l) {
    __builtin_amdgcn_global_load_lds((av1_t*)g, (av3_t*)l, 16, 0, 0);
}

// ---------------- shared GEMM body ----------------
// C[M,N] = A[M,K] * B[N,K]^T, 4 waves (2x2), BK=64, gl16 staging for bf16,
// XOR-swizzled LDS. As: BM*64 shorts, Bs: BN*64 shorts, invL: BM floats.
// EPI: 1 = bf16 C*cscale
//      2 = QK: e=mask?0:exp(C); bf16 e + per-row partial sums psum[row][32]
//      3 = PV: f32 C * (1/sum(psum row))
template<int BM, int BN, bool AF32, int EPI>
__device__ __forceinline__ void gemm_body(
    const void* __restrict__ Ap, const short* __restrict__ Bp,
    void* __restrict__ Cp, int M, int N, int K, long sA, long sB, long sC,
    float cscale, const unsigned char* __restrict__ mask,
    float* __restrict__ psum, int bx, int by, int b,
    short* As, short* Bs, float* invL)
{
    constexpr int WM = BM / 2, WN = BN / 2, FM = WM / 16, FN = WN / 16;
    const int m0 = by * BM, n0 = bx * BN;

    const int t = threadIdx.x, w = t >> 6, l = t & 63;
    const int wm = w >> 1, wn = w & 1, rl = l & 15, kg = l >> 4;

    const int srow = t >> 3;
    const int schunk = t & 7;
    const int gchunk = schunk ^ (srow & 7);

    const short* Bg0 = Bp + (long)b * sB + (long)(n0 + srow) * K + gchunk * 8;
    char* AsP = (char*)As + t * 16;
    char* BsP = (char*)Bs + t * 16;

    const int ch0 = ((0 | kg) ^ (rl & 7)) * 16;
    const int ch1 = ((4 | kg) ^ (rl & 7)) * 16;

    if constexpr (EPI == 3) {   // denominators: overlap with first staging
        if (t < BM) {
            const float* pp = psum + ((long)b * M + m0 + t) * 32;
            float s = 0.f;
            #pragma unroll
            for (int j = 0; j < 32; j++) s += pp[j];
            invL[t] = 1.0f / s;
        }
    }

    f32x4 acc[FM][FN];
    #pragma unroll
    for (int mi = 0; mi < FM; mi++)
        #pragma unroll
        for (int ni = 0; ni < FN; ni++)
            acc[mi][ni] = (f32x4){0.f, 0.f, 0.f, 0.f};

    for (int k0 = 0; k0 < K; k0 += 64) {
        if (AF32) {
            #pragma unroll
            for (int j = 0; j < BM / 32; j++) {
                const float* ag = (const float*)Ap + (long)b * sA +
                                  (long)(m0 + j * 32 + srow) * K + k0 + schunk * 8;
                float4 v0 = *(const float4*)ag;
                float4 v1 = *(const float4*)(ag + 4);
                short8 sv;
                sv[0]=f2bf(v0.x); sv[1]=f2bf(v0.y); sv[2]=f2bf(v0.z); sv[3]=f2bf(v0.w);
                sv[4]=f2bf(v1.x); sv[5]=f2bf(v1.y); sv[6]=f2bf(v1.z); sv[7]=f2bf(v1.w);
                *(short8*)&As[(j * 32 + srow) * 64 + (schunk ^ (srow & 7)) * 8] = sv;
            }
        } else {
            const short* Ag0 = (const short*)Ap + (long)b * sA +
                               (long)(m0 + srow) * K + k0 + gchunk * 8;
            #pragma unroll
            for (int j = 0; j < BM / 32; j++)
                gl16(Ag0 + (long)j * 32 * K, AsP + j * 4096);
        }
        #pragma unroll
        for (int j = 0; j < BN / 32; j++)
            gl16(Bg0 + k0 + (long)j * 32 * K, BsP + j * 4096);
        __syncthreads();

        #pragma unroll
        for (int kh = 0; kh < 2; kh++) {
            const int ch = kh ? ch1 : ch0;
            short8 a[FM], bb[FN];
            #pragma unroll
            for (int mi = 0; mi < FM; mi++)
                a[mi] = *(short8*)((char*)&As[(wm * WM + mi * 16 + rl) * 64] + ch);
            #pragma unroll
            for (int ni = 0; ni < FN; ni++)
                bb[ni] = *(short8*)((char*)&Bs[(wn * WN + ni * 16 + rl) * 64] + ch);
            #pragma unroll
            for (int mi = 0; mi < FM; mi++)
                #pragma unroll
                for (int ni = 0; ni < FN; ni++)
                    acc[mi][ni] = __builtin_amdgcn_mfma_f32_16x16x32_bf16(
                        a[mi], bb[ni], acc[mi][ni], 0, 0, 0);
        }
        __syncthreads();
    }

    const int rowb = m0 + wm * WM + kg * 4;

    if constexpr (EPI == 2) {
        float* psL = (float*)As;  // [2][BM]
        float pr[FM][4];
        #pragma unroll
        for (int mi = 0; mi < FM; mi++)
            #pragma unroll
            for (int i = 0; i < 4; i++) pr[mi][i] = 0.f;
        #pragma unroll
        for (int mi = 0; mi < FM; mi++)
            #pragma unroll
            for (int ni = 0; ni < FN; ni++) {
                const int n = n0 + wn * WN + ni * 16 + rl;
                const bool mk = mask[(long)b * N + n] != 0;
                #pragma unroll
                for (int i = 0; i < 4; i++) {
                    const float e = mk ? 0.f : __expf(acc[mi][ni][i]);
                    ((short*)Cp)[(long)b * sC + (long)(rowb + mi * 16 + i) * N + n] = f2bf(e);
                    pr[mi][i] += e;
                }
            }
        #pragma unroll
        for (int off = 1; off < 16; off <<= 1)
            #pragma unroll
            for (int mi = 0; mi < FM; mi++)
                #pragma unroll
                for (int i = 0; i < 4; i++)
                    pr[mi][i] += __shfl_xor(pr[mi][i], off);
        if (rl == 0) {
            #pragma unroll
            for (int mi = 0; mi < FM; mi++)
                #pragma unroll
                for (int i = 0; i < 4; i++)
                    psL[wn * BM + wm * WM + mi * 16 + kg * 4 + i] = pr[mi][i];
        }
        __syncthreads();
        if (t < BM)
            psum[((long)b * M + m0 + t) * 32 + bx] = psL[t] + psL[BM + t];
        return;
    }

    #pragma unroll
    for (int mi = 0; mi < FM; mi++)
        #pragma unroll
        for (int ni = 0; ni < FN; ni++) {
            const int n = n0 + wn * WN + ni * 16 + rl;
            #pragma unroll
            for (int i = 0; i < 4; i++) {
                const long idx = (long)b * sC + (long)(rowb + mi * 16 + i) * N + n;
                if constexpr (EPI == 1)
                    ((short*)Cp)[idx] = f2bf(acc[mi][ni][i] * cscale);
                else  // EPI == 3
                    ((float*)Cp)[idx] = acc[mi][ni][i] *
                                        invL[wm * WM + mi * 16 + kg * 4 + i];
            }
        }
}

// ---------------- transpose bodies ----------------
__device__ __forceinline__ void transpose32_body(
    const float* __restrict__ s, short* __restrict__ d,
    int R, int C, int r0, int c0, float* tile /*32x33*/)
{
    const int x = threadIdx.x & 31, y = threadIdx.x >> 5;
    #pragma unroll
    for (int i = 0; i < 32; i += 8)
        tile[(y + i) * 33 + x] = s[(long)(r0 + y + i) * C + (c0 + x)];
    __syncthreads();
    #pragma unroll
    for (int i = 0; i < 32; i += 8)
        d[(long)(c0 + y + i) * R + (r0 + x)] = f2bf(tile[x * 33 + y + i]);
}

__device__ __forceinline__ void transpose64_body(
    const float* __restrict__ s, short* __restrict__ d,
    int R, int C, int r0, int c0, float* tile /*64x65*/)
{
    const int x = threadIdx.x & 63, y = threadIdx.x >> 6;
    #pragma unroll
    for (int i = 0; i < 64; i += 4)
        tile[(y + i) * 65 + x] = s[(long)(r0 + y + i) * C + (c0 + x)];
    __syncthreads();
    #pragma unroll
    for (int i = 0; i < 64; i += 4)
        d[(long)(c0 + y + i) * R + (r0 + x)] = f2bf(tile[x * 65 + y + i]);
}

// ---------------- kernels ----------------
// Phase A: both weight transposes. blocks: Wk 32x8=256, Wq 24x8=192.
__global__ __launch_bounds__(256) void k_weights(
    const float* __restrict__ Wk, short* __restrict__ WkT,
    const float* __restrict__ Wq, short* __restrict__ WqT)
{
    __shared__ float tile[32 * 33];
    const int f = blockIdx.x;
    if (f < 256) {
        transpose32_body(Wk, WkT, DH_, P_, (f & 31) * 32, (f >> 5) * 32, tile);
    } else {
        const int f2 = f - 256;
        transpose32_body(Wq, WqT, DG_, P_, (f2 % 24) * 32, (f2 / 24) * 32, tile);
    }
}

// Phase B: K-proj (512 blocks) + Q-proj (128) + Ht transpose (4096).
__global__ __launch_bounds__(256) void k_phaseB(
    const float* __restrict__ H, const float* __restrict__ G,
    const short* __restrict__ WkT, const short* __restrict__ WqT,
    short* __restrict__ Kb, short* __restrict__ Qb, short* __restrict__ Ht)
{
    __shared__ __align__(16) char smem[4096 + 32768 + 128];
    const int f = blockIdx.x;
    if (f < 512) {
        gemm_body<32, 256, true, 1>(
            H, WkT, Kb, L_, P_, DH_, (long)L_ * DH_, 0, (long)L_ * P_,
            1.0f, nullptr, nullptr, 0, f & 63, f >> 6,
            (short*)smem, (short*)(smem + 4096), (float*)(smem + 4096 + 32768));
    } else if (f < 640) {
        const int f2 = f - 512;
        gemm_body<32, 256, true, 1>(
            G, WqT, Qb, T_, P_, DG_, (long)T_ * DG_, 0, (long)T_ * P_,
            0.0625f, nullptr, nullptr, 0, f2 & 15, f2 >> 4,
            (short*)smem, (short*)(smem + 4096), (float*)(smem + 4096 + 32768));
    } else {
        const int f3 = f - 640;           // 32 x 16 x 8
        const int tx = f3 & 31, ty = (f3 >> 5) & 15, b = f3 >> 9;
        transpose64_body(H + (long)b * L_ * DH_, Ht + (long)b * DH_ * L_,
                         L_, DH_, tx * 64, ty * 64, (float*)smem);
    }
}

// Phase C: e = exp(Q K^T) (mask->0) + row partial sums. 1024 blocks.
__global__ __launch_bounds__(256) void k_qk(
    const short* __restrict__ Qb, const short* __restrict__ Kb,
    short* __restrict__ alpha, const unsigned char* __restrict__ mask,
    float* __restrict__ psum)
{
    __shared__ __align__(16) short As[128 * 64];
    __shared__ __align__(16) short Bs[64 * 64];
    const int gx = gridDim.x, gy = gridDim.y;
    const int nwg = gx * gy * (int)gridDim.z;
    int flat = blockIdx.x + gx * (blockIdx.y + gy * blockIdx.z);
    flat = (flat & 7) * (nwg >> 3) + (flat >> 3);
    const int bx = flat % gx, by = (flat / gx) % gy, b = flat / (gx * gy);
    gemm_body<128, 64, false, 2>(
        Qb, Kb, alpha, T_, L_, P_, (long)T_ * P_, (long)L_ * P_, (long)T_ * L_,
        1.0f, mask, psum, bx, by, b, As, Bs, nullptr);
}

// Phase D: Z = (e @ H) / rowsum(e). 512 blocks.
__global__ __launch_bounds__(256) void k_pv(
    const short* __restrict__ alpha, const short* __restrict__ Ht,
    float* __restrict__ Z, float* __restrict__ psum)
{
    __shared__ __align__(16) short As[128 * 64];
    __shared__ __align__(16) short Bs[64 * 64];
    __shared__ float invL[128];
    const int gx = gridDim.x, gy = gridDim.y;
    const int nwg = gx * gy * (int)gridDim.z;
    int flat = blockIdx.x + gx * (blockIdx.y + gy * blockIdx.z);
    flat = (flat & 7) * (nwg >> 3) + (flat >> 3);
    const int bx = flat % gx, by = (flat / gx) % gy, b = flat / (gx * gy);
    gemm_body<128, 64, false, 3>(
        alpha, Ht, Z, T_, DH_, L_, (long)T_ * L_, (long)DH_ * L_, (long)T_ * DH_,
        1.0f, nullptr, psum, bx, by, b, As, Bs, invL);
}

extern "C" void kernel_launch(void* const* d_in, const int* in_sizes, int n_in,
                              void* d_out, int out_size, void* d_ws, size_t ws_size,
                              hipStream_t stream)
{
    const float* H  = (const float*)d_in[0];
    const float* G  = (const float*)d_in[1];
    const float* Wk = (const float*)d_in[2];
    const float* Wq = (const float*)d_in[3];
    const unsigned char* mask = (const unsigned char*)d_in[4];
    float* Z = (float*)d_out;

    char* ws = (char*)d_ws;
    const long OFF_WKT   = 0;                       // 256x1024 bf16 = 512 KB
    const long OFF_WQT   = 524288;                  // 256x768  bf16 = 384 KB
    const long OFF_HT    = 917504;                  // 8x1024x2048 bf16 = 32 MB
    const long OFF_KB    = OFF_HT + 33554432;       // 8x2048x256 bf16 = 8 MB
    const long OFF_QB    = OFF_KB + 8388608;        // 8x512x256 bf16 = 2 MB
    const long OFF_ALPHA = OFF_QB + 2097152;        // 8x512x2048 bf16 = 16 MB
    const long OFF_PSUM  = OFF_ALPHA + 16777216;    // 8x512x32 f32 = 512 KB
    short* WkT   = (short*)(ws + OFF_WKT);
    short* WqT   = (short*)(ws + OFF_WQT);
    short* Ht    = (short*)(ws + OFF_HT);
    short* Kb    = (short*)(ws + OFF_KB);
    short* Qb    = (short*)(ws + OFF_QB);
    short* alpha = (short*)(ws + OFF_ALPHA);        // unnormalized e = exp(logit)
    float* psum  = (float*)(ws + OFF_PSUM);

    // A: weight transposes (448 blocks)
    k_weights<<<dim3(448), 256, 0, stream>>>(Wk, WkT, Wq, WqT);

    // B: K-proj + Q-proj + Ht transpose, one launch (4736 blocks)
    k_phaseB<<<dim3(4736), 256, 0, stream>>>(H, G, WkT, WqT, Kb, Qb, Ht);

    // C: QK + exp + partial sums
    k_qk<<<dim3(L_/64, T_/128, B_), 256, 0, stream>>>(Qb, Kb, alpha, mask, psum);

    // D: PV + normalize
    k_pv<<<dim3(DH_/64, T_/128, B_), 256, 0, stream>>>(alpha, Ht, Z, psum);
}